// Round 1
// baseline (8649.493 us; speedup 1.0000x reference)
//
#include <hip/hip_runtime.h>

#define NN 50000
#define NE 1600000
#define DD 128
#define GG 512
#define BN_EPS 1e-5f

// ---------------- copy h rows (stride hstride) into m [N,128] ----------------
__global__ __launch_bounds__(256) void copy_rows_k(const float* __restrict__ h, int hstride,
                                                   float* __restrict__ m) {
    int i = blockIdx.x * blockDim.x + threadIdx.x;
    const int tot = NN * 32;
    const int stp = gridDim.x * blockDim.x;
    for (; i < tot; i += stp) {
        int n = i >> 5, c = i & 31;
        float4 v = *(const float4*)(h + (size_t)n * hstride + c * 4);
        ((float4*)m)[i] = v;
    }
}

// ---------------- scatter-add: m[dst] += h[src] ------------------------------
__global__ __launch_bounds__(256) void scatter_k(const int* __restrict__ src, const int* __restrict__ dst,
                                                 const float* __restrict__ h, int hstride,
                                                 float* __restrict__ m) {
    int gid = blockIdx.x * blockDim.x + threadIdx.x;
    int e = gid >> 5;            // one edge per 32 lanes
    int l = gid & 31;            // lane handles float4 l
    const int estp = (gridDim.x * blockDim.x) >> 5;
    for (; e < NE; e += estp) {
        int s = src[e], d = dst[e];
        float4 v = *(const float4*)(h + (size_t)s * hstride + l * 4);
        float* o = m + (size_t)d * DD + l * 4;
        atomicAdd(o + 0, v.x);
        atomicAdd(o + 1, v.y);
        atomicAdd(o + 2, v.z);
        atomicAdd(o + 3, v.w);
    }
}

// ---------------- GEMM [N,128]@[128,128] + bias + relu (+BN stats) -----------
// Column-split: blockIdx.y in {0,1} handles 64 output cols. W half in LDS.
#define GROWS 16
__global__ __launch_bounds__(256) void mlp_gemm_k(const float* __restrict__ in, float* __restrict__ outp,
                                                  const float* __restrict__ W, const float* __restrict__ bias,
                                                  float* __restrict__ stats) {
    __shared__ float sW[128 * 64];      // 32 KB
    __shared__ float srow[GROWS * 128]; // 8 KB
    const int tid = threadIdx.x;
    const int col_off = blockIdx.y * 64;
    for (int i = tid; i < 128 * 16; i += 256) {
        int r = i >> 4, c4 = i & 15;
        ((float4*)(sW + r * 64))[c4] = *(const float4*)(W + r * 128 + col_off + c4 * 4);
    }
    const int slot = tid >> 4;        // 0..15 row slot
    const int d4 = (tid & 15) * 4;    // output col base within 64
    float4 bv = *(const float4*)(bias + col_off + d4);
    float4 sacc = {0.f,0.f,0.f,0.f}, qacc = {0.f,0.f,0.f,0.f};
    __syncthreads();
    for (int row0 = blockIdx.x * GROWS; row0 < NN; row0 += gridDim.x * GROWS) {
        for (int i = tid; i < GROWS * 32; i += 256) {
            int r = i >> 5, c = i & 31;
            if (row0 + r < NN)
                ((float4*)(srow + r * 128))[c] = ((const float4*)(in + (size_t)(row0 + r) * 128))[c];
        }
        __syncthreads();
        if (row0 + slot < NN) {
            float4 acc = bv;
            const float* mr = srow + slot * 128;
            #pragma unroll 8
            for (int k = 0; k < 128; ++k) {
                float mv = mr[k];
                float4 w = *(const float4*)(sW + k * 64 + d4);
                acc.x = fmaf(mv, w.x, acc.x);
                acc.y = fmaf(mv, w.y, acc.y);
                acc.z = fmaf(mv, w.z, acc.z);
                acc.w = fmaf(mv, w.w, acc.w);
            }
            acc.x = fmaxf(acc.x, 0.f);
            acc.y = fmaxf(acc.y, 0.f);
            acc.z = fmaxf(acc.z, 0.f);
            acc.w = fmaxf(acc.w, 0.f);
            *(float4*)(outp + (size_t)(row0 + slot) * 128 + col_off + d4) = acc;
            if (stats) {
                sacc.x += acc.x; sacc.y += acc.y; sacc.z += acc.z; sacc.w += acc.w;
                qacc.x += acc.x*acc.x; qacc.y += acc.y*acc.y; qacc.z += acc.z*acc.z; qacc.w += acc.w*acc.w;
            }
        }
        __syncthreads();
    }
    if (stats) {
        // all sW reads finished (final barrier of loop) -> reuse as reduction space
        ((float4*)(sW + slot * 64))[tid & 15] = sacc;
        ((float4*)(sW + 1024 + slot * 64))[tid & 15] = qacc;
        __syncthreads();
        if (slot == 0) {
            float4 ts = {0.f,0.f,0.f,0.f}, tq = {0.f,0.f,0.f,0.f};
            for (int r = 0; r < GROWS; ++r) {
                float4 a = ((float4*)(sW + r * 64))[tid];
                float4 b = ((float4*)(sW + 1024 + r * 64))[tid];
                ts.x += a.x; ts.y += a.y; ts.z += a.z; ts.w += a.w;
                tq.x += b.x; tq.y += b.y; tq.z += b.z; tq.w += b.w;
            }
            atomicAdd(&stats[col_off + d4 + 0], ts.x);
            atomicAdd(&stats[col_off + d4 + 1], ts.y);
            atomicAdd(&stats[col_off + d4 + 2], ts.z);
            atomicAdd(&stats[col_off + d4 + 3], ts.w);
            atomicAdd(&stats[128 + col_off + d4 + 0], tq.x);
            atomicAdd(&stats[128 + col_off + d4 + 1], tq.y);
            atomicAdd(&stats[128 + col_off + d4 + 2], tq.z);
            atomicAdd(&stats[128 + col_off + d4 + 3], tq.w);
        }
    }
}

// ---------------- BN finalize: scale/shift from stats ------------------------
__global__ void bn_finalize_k(const float* __restrict__ stats, const float* __restrict__ gamma,
                              const float* __restrict__ beta, float* __restrict__ ss) {
    int d = threadIdx.x;
    float mu = stats[d] * (1.0f / NN);
    float var = stats[128 + d] * (1.0f / NN) - mu * mu;
    float sc = gamma[d] * rsqrtf(var + BN_EPS);
    ss[d] = sc;
    ss[128 + d] = beta[d] - mu * sc;
}

// ---------------- BN apply: node[:, loff:loff+128] = y*sc+sh -----------------
__global__ __launch_bounds__(256) void bn_apply_k(const float* __restrict__ y, const float* __restrict__ ss,
                                                  float* __restrict__ node, int loff) {
    int i = blockIdx.x * blockDim.x + threadIdx.x;
    const int tot = NN * 32;
    const int stp = gridDim.x * blockDim.x;
    for (; i < tot; i += stp) {
        int n = i >> 5, c = i & 31;
        float4 v = ((const float4*)y)[i];
        int d = c * 4;
        float4 sc = *(const float4*)(ss + d);
        float4 sh = *(const float4*)(ss + 128 + d);
        v.x = fmaf(v.x, sc.x, sh.x);
        v.y = fmaf(v.y, sc.y, sh.y);
        v.z = fmaf(v.z, sc.z, sh.z);
        v.w = fmaf(v.w, sc.w, sh.w);
        *(float4*)(node + (size_t)n * 384 + loff + d) = v;
    }
}

// ---------------- pool: per-graph sum of contiguous node rows ----------------
__global__ __launch_bounds__(128) void pool_k(const float* __restrict__ node, const int* __restrict__ batch,
                                              float* __restrict__ pooled) {
    int g = blockIdx.x;
    // lower_bound(batch, g) and lower_bound(batch, g+1)
    int lo = 0, hi = NN;
    while (lo < hi) { int mid = (lo + hi) >> 1; if (batch[mid] < g) lo = mid + 1; else hi = mid; }
    int s = lo;
    lo = s; hi = NN;
    while (lo < hi) { int mid = (lo + hi) >> 1; if (batch[mid] < g + 1) lo = mid + 1; else hi = mid; }
    int e = lo;
    int t = threadIdx.x;
    float a0 = 0.f, a1 = 0.f, a2 = 0.f;
    for (int n = s; n < e; ++n) {
        const float* row = node + (size_t)n * 384;
        a0 += row[t];
        a1 += row[t + 128];
        a2 += row[t + 256];
    }
    pooled[(size_t)g * 384 + t] = a0;
    pooled[(size_t)g * 384 + t + 128] = a1;
    pooled[(size_t)g * 384 + t + 256] = a2;
}

// ---------------- projection head: relu(p@Wp1+bp1)@Wp2+bp2 -------------------
__global__ __launch_bounds__(384) void proj_k(const float* __restrict__ pooled,
                                              const float* __restrict__ Wp1, const float* __restrict__ bp1,
                                              const float* __restrict__ Wp2, const float* __restrict__ bp2,
                                              float* __restrict__ out) {
    __shared__ float p[384];
    __shared__ float t1[384];
    int g = blockIdx.x, t = threadIdx.x;
    p[t] = pooled[(size_t)g * 384 + t];
    __syncthreads();
    float acc = bp1[t];
    #pragma unroll 4
    for (int k = 0; k < 384; ++k) acc = fmaf(p[k], Wp1[(size_t)k * 384 + t], acc);
    t1[t] = fmaxf(acc, 0.f);
    __syncthreads();
    float acc2 = bp2[t];
    #pragma unroll 4
    for (int k = 0; k < 384; ++k) acc2 = fmaf(t1[k], Wp2[(size_t)k * 384 + t], acc2);
    out[(size_t)g * 384 + t] = acc2;
}

extern "C" void kernel_launch(void* const* d_in, const int* in_sizes, int n_in,
                              void* d_out, int out_size, void* d_ws, size_t ws_size,
                              hipStream_t stream) {
    const float* x     = (const float*)d_in[0];
    const int*   ei    = (const int*)d_in[1];
    const int*   srcI  = ei;
    const int*   dstI  = ei + NE;
    const int*   batch = (const int*)d_in[2];
    const float* W1    = (const float*)d_in[3];
    const float* b1    = (const float*)d_in[4];
    const float* W2    = (const float*)d_in[5];
    const float* b2    = (const float*)d_in[6];
    const float* gamma = (const float*)d_in[7];
    const float* beta  = (const float*)d_in[8];
    const float* Wp1   = (const float*)d_in[9];
    const float* bp1   = (const float*)d_in[10];
    const float* Wp2   = (const float*)d_in[11];
    const float* bp2   = (const float*)d_in[12];
    float* out = (float*)d_out;

    float* m_buf  = (float*)d_ws;                    // N*128
    float* t_buf  = m_buf + (size_t)NN * 128;        // N*128
    float* node   = t_buf + (size_t)NN * 128;        // N*384
    float* pooled = node + (size_t)NN * 384;         // G*384
    float* stats  = pooled + (size_t)GG * 384;       // 256
    float* ss     = stats + 256;                     // 256

    for (int l = 0; l < 3; ++l) {
        const float* h;
        int hstride;
        if (l == 0) { h = x; hstride = 128; }
        else        { h = node + (l - 1) * 128; hstride = 384; }

        copy_rows_k<<<1024, 256, 0, stream>>>(h, hstride, m_buf);
        scatter_k<<<2048, 256, 0, stream>>>(srcI, dstI, h, hstride, m_buf);
        hipMemsetAsync(stats, 0, 256 * sizeof(float), stream);
        {
            dim3 gg(512, 2);
            mlp_gemm_k<<<gg, 256, 0, stream>>>(m_buf, t_buf, W1 + (size_t)l * 128 * 128, b1 + l * 128, nullptr);
            mlp_gemm_k<<<gg, 256, 0, stream>>>(t_buf, m_buf, W2 + (size_t)l * 128 * 128, b2 + l * 128, stats);
        }
        bn_finalize_k<<<1, 128, 0, stream>>>(stats, gamma + l * 128, beta + l * 128, ss);
        bn_apply_k<<<1024, 256, 0, stream>>>(m_buf, ss, node, l * 128);
    }

    pool_k<<<GG, 128, 0, stream>>>(node, batch, pooled);
    proj_k<<<GG, 384, 0, stream>>>(pooled, Wp1, bp1, Wp2, bp2, out);
}

// Round 2
// 1117.158 us; speedup vs baseline: 7.7424x; 7.7424x over previous
//
#include <hip/hip_runtime.h>

#define NN 50000
#define NE 1600000
#define DD 128
#define GG 512
#define BN_EPS 1e-5f
#define NB_SCAN 196   // ceil(NN/256)

// ---------------- CSR build ----------------
__global__ __launch_bounds__(256) void hist_k(const int* __restrict__ dst, int* __restrict__ deg) {
    int e = blockIdx.x * blockDim.x + threadIdx.x;
    int stp = gridDim.x * blockDim.x;
    for (; e < NE; e += stp) atomicAdd(&deg[dst[e]], 1);
}

__global__ __launch_bounds__(256) void scan1_k(const int* __restrict__ deg, int* __restrict__ bsum) {
    __shared__ int s[256];
    int t = threadIdx.x, i = blockIdx.x * 256 + t;
    s[t] = (i < NN) ? deg[i] : 0;
    __syncthreads();
    for (int o = 128; o > 0; o >>= 1) {
        if (t < o) s[t] += s[t + o];
        __syncthreads();
    }
    if (t == 0) bsum[blockIdx.x] = s[0];
}

__global__ __launch_bounds__(256) void scan2_k(const int* __restrict__ bsum, int* __restrict__ boff) {
    __shared__ int s[256];
    int t = threadIdx.x;
    int v = (t < NB_SCAN) ? bsum[t] : 0;
    s[t] = v;
    __syncthreads();
    for (int o = 1; o < 256; o <<= 1) {
        int u = (t >= o) ? s[t - o] : 0;
        __syncthreads();
        s[t] += u;
        __syncthreads();
    }
    if (t < NB_SCAN) boff[t] = s[t] - v;   // exclusive
}

__global__ __launch_bounds__(256) void scan3_k(const int* __restrict__ deg, const int* __restrict__ boff,
                                               int* __restrict__ rowptr, int* __restrict__ cursor) {
    __shared__ int s[256];
    int t = threadIdx.x, i = blockIdx.x * 256 + t;
    int v = (i < NN) ? deg[i] : 0;
    s[t] = v;
    __syncthreads();
    for (int o = 1; o < 256; o <<= 1) {
        int u = (t >= o) ? s[t - o] : 0;
        __syncthreads();
        s[t] += u;
        __syncthreads();
    }
    if (i < NN) {
        int st = boff[blockIdx.x] + s[t] - v;
        rowptr[i] = st;
        cursor[i] = st;
    }
    if (i == NN - 1) rowptr[NN] = NE;
}

__global__ __launch_bounds__(256) void fill_k(const int* __restrict__ src, const int* __restrict__ dst,
                                              int* __restrict__ cursor, int* __restrict__ csr) {
    int e = blockIdx.x * blockDim.x + threadIdx.x;
    int stp = gridDim.x * blockDim.x;
    for (; e < NE; e += stp) {
        int p = atomicAdd(&cursor[dst[e]], 1);
        csr[p] = src[e];
    }
}

// ---------------- aggregation: m[n] = h[n] + sum_{j->n} h[j] -----------------
__global__ __launch_bounds__(256) void agg_k(const int* __restrict__ rowptr, const int* __restrict__ csr,
                                             const float* __restrict__ h, int hstride,
                                             float* __restrict__ m) {
    int gid = blockIdx.x * 256 + threadIdx.x;
    int grp = gid >> 5, l = gid & 31;
    int ngrp = (gridDim.x * 256) >> 5;
    for (int n = grp; n < NN; n += ngrp) {
        int s = rowptr[n], e = rowptr[n + 1];
        float4 acc = *(const float4*)(h + (size_t)n * hstride + l * 4);
        int i = s;
        for (; i + 1 < e; i += 2) {
            int s0 = csr[i], s1 = csr[i + 1];
            float4 v0 = *(const float4*)(h + (size_t)s0 * hstride + l * 4);
            float4 v1 = *(const float4*)(h + (size_t)s1 * hstride + l * 4);
            acc.x += v0.x + v1.x;
            acc.y += v0.y + v1.y;
            acc.z += v0.z + v1.z;
            acc.w += v0.w + v1.w;
        }
        if (i < e) {
            int s0 = csr[i];
            float4 v0 = *(const float4*)(h + (size_t)s0 * hstride + l * 4);
            acc.x += v0.x; acc.y += v0.y; acc.z += v0.z; acc.w += v0.w;
        }
        *(float4*)(m + (size_t)n * DD + l * 4) = acc;
    }
}

// ---------------- GEMM [N,128]@[128,128] + bias + relu (+BN stats) -----------
#define GROWS 16
__global__ __launch_bounds__(256) void mlp_gemm_k(const float* __restrict__ in, float* __restrict__ outp,
                                                  const float* __restrict__ W, const float* __restrict__ bias,
                                                  float* __restrict__ stats) {
    __shared__ float sW[128 * 64];      // 32 KB
    __shared__ float srow[GROWS * 128]; // 8 KB
    const int tid = threadIdx.x;
    const int col_off = blockIdx.y * 64;
    for (int i = tid; i < 128 * 16; i += 256) {
        int r = i >> 4, c4 = i & 15;
        ((float4*)(sW + r * 64))[c4] = *(const float4*)(W + r * 128 + col_off + c4 * 4);
    }
    const int slot = tid >> 4;        // 0..15 row slot
    const int d4 = (tid & 15) * 4;    // output col base within 64
    float4 bv = *(const float4*)(bias + col_off + d4);
    float4 sacc = {0.f,0.f,0.f,0.f}, qacc = {0.f,0.f,0.f,0.f};
    __syncthreads();
    for (int row0 = blockIdx.x * GROWS; row0 < NN; row0 += gridDim.x * GROWS) {
        for (int i = tid; i < GROWS * 32; i += 256) {
            int r = i >> 5, c = i & 31;
            if (row0 + r < NN)
                ((float4*)(srow + r * 128))[c] = ((const float4*)(in + (size_t)(row0 + r) * 128))[c];
        }
        __syncthreads();
        if (row0 + slot < NN) {
            float4 acc = bv;
            const float* mr = srow + slot * 128;
            #pragma unroll 8
            for (int k = 0; k < 128; ++k) {
                float mv = mr[k];
                float4 w = *(const float4*)(sW + k * 64 + d4);
                acc.x = fmaf(mv, w.x, acc.x);
                acc.y = fmaf(mv, w.y, acc.y);
                acc.z = fmaf(mv, w.z, acc.z);
                acc.w = fmaf(mv, w.w, acc.w);
            }
            acc.x = fmaxf(acc.x, 0.f);
            acc.y = fmaxf(acc.y, 0.f);
            acc.z = fmaxf(acc.z, 0.f);
            acc.w = fmaxf(acc.w, 0.f);
            *(float4*)(outp + (size_t)(row0 + slot) * 128 + col_off + d4) = acc;
            if (stats) {
                sacc.x += acc.x; sacc.y += acc.y; sacc.z += acc.z; sacc.w += acc.w;
                qacc.x += acc.x*acc.x; qacc.y += acc.y*acc.y; qacc.z += acc.z*acc.z; qacc.w += acc.w*acc.w;
            }
        }
        __syncthreads();
    }
    if (stats) {
        ((float4*)(sW + slot * 64))[tid & 15] = sacc;
        ((float4*)(sW + 1024 + slot * 64))[tid & 15] = qacc;
        __syncthreads();
        if (slot == 0) {
            float4 ts = {0.f,0.f,0.f,0.f}, tq = {0.f,0.f,0.f,0.f};
            for (int r = 0; r < GROWS; ++r) {
                float4 a = ((float4*)(sW + r * 64))[tid];
                float4 b = ((float4*)(sW + 1024 + r * 64))[tid];
                ts.x += a.x; ts.y += a.y; ts.z += a.z; ts.w += a.w;
                tq.x += b.x; tq.y += b.y; tq.z += b.z; tq.w += b.w;
            }
            atomicAdd(&stats[col_off + d4 + 0], ts.x);
            atomicAdd(&stats[col_off + d4 + 1], ts.y);
            atomicAdd(&stats[col_off + d4 + 2], ts.z);
            atomicAdd(&stats[col_off + d4 + 3], ts.w);
            atomicAdd(&stats[128 + col_off + d4 + 0], tq.x);
            atomicAdd(&stats[128 + col_off + d4 + 1], tq.y);
            atomicAdd(&stats[128 + col_off + d4 + 2], tq.z);
            atomicAdd(&stats[128 + col_off + d4 + 3], tq.w);
        }
    }
}

// ---------------- BN finalize ----------------
__global__ void bn_finalize_k(const float* __restrict__ stats, const float* __restrict__ gamma,
                              const float* __restrict__ beta, float* __restrict__ ss) {
    int d = threadIdx.x;
    float mu = stats[d] * (1.0f / NN);
    float var = stats[128 + d] * (1.0f / NN) - mu * mu;
    float sc = gamma[d] * rsqrtf(var + BN_EPS);
    ss[d] = sc;
    ss[128 + d] = beta[d] - mu * sc;
}

// ---------------- BN apply -> node[:, loff:loff+128] ----------------
__global__ __launch_bounds__(256) void bn_apply_k(const float* __restrict__ y, const float* __restrict__ ss,
                                                  float* __restrict__ node, int loff) {
    int i = blockIdx.x * blockDim.x + threadIdx.x;
    const int tot = NN * 32;
    const int stp = gridDim.x * blockDim.x;
    for (; i < tot; i += stp) {
        int n = i >> 5, c = i & 31;
        float4 v = ((const float4*)y)[i];
        int d = c * 4;
        float4 sc = *(const float4*)(ss + d);
        float4 sh = *(const float4*)(ss + 128 + d);
        v.x = fmaf(v.x, sc.x, sh.x);
        v.y = fmaf(v.y, sc.y, sh.y);
        v.z = fmaf(v.z, sc.z, sh.z);
        v.w = fmaf(v.w, sc.w, sh.w);
        *(float4*)(node + (size_t)n * 384 + loff + d) = v;
    }
}

// ---------------- pool: per-graph sum (batch sorted) ----------------
__global__ __launch_bounds__(128) void pool_k(const float* __restrict__ node, const int* __restrict__ batch,
                                              float* __restrict__ pooled) {
    int g = blockIdx.x;
    int lo = 0, hi = NN;
    while (lo < hi) { int mid = (lo + hi) >> 1; if (batch[mid] < g) lo = mid + 1; else hi = mid; }
    int s = lo;
    lo = s; hi = NN;
    while (lo < hi) { int mid = (lo + hi) >> 1; if (batch[mid] < g + 1) lo = mid + 1; else hi = mid; }
    int e = lo;
    int t = threadIdx.x;
    float a0 = 0.f, a1 = 0.f, a2 = 0.f;
    for (int n = s; n < e; ++n) {
        const float* row = node + (size_t)n * 384;
        a0 += row[t];
        a1 += row[t + 128];
        a2 += row[t + 256];
    }
    pooled[(size_t)g * 384 + t] = a0;
    pooled[(size_t)g * 384 + t + 128] = a1;
    pooled[(size_t)g * 384 + t + 256] = a2;
}

// ---------------- projection head ----------------
__global__ __launch_bounds__(384) void proj_k(const float* __restrict__ pooled,
                                              const float* __restrict__ Wp1, const float* __restrict__ bp1,
                                              const float* __restrict__ Wp2, const float* __restrict__ bp2,
                                              float* __restrict__ out) {
    __shared__ float p[384];
    __shared__ float t1[384];
    int g = blockIdx.x, t = threadIdx.x;
    p[t] = pooled[(size_t)g * 384 + t];
    __syncthreads();
    float acc = bp1[t];
    #pragma unroll 4
    for (int k = 0; k < 384; ++k) acc = fmaf(p[k], Wp1[(size_t)k * 384 + t], acc);
    t1[t] = fmaxf(acc, 0.f);
    __syncthreads();
    float acc2 = bp2[t];
    #pragma unroll 4
    for (int k = 0; k < 384; ++k) acc2 = fmaf(t1[k], Wp2[(size_t)k * 384 + t], acc2);
    out[(size_t)g * 384 + t] = acc2;
}

extern "C" void kernel_launch(void* const* d_in, const int* in_sizes, int n_in,
                              void* d_out, int out_size, void* d_ws, size_t ws_size,
                              hipStream_t stream) {
    const float* x     = (const float*)d_in[0];
    const int*   ei    = (const int*)d_in[1];
    const int*   srcI  = ei;
    const int*   dstI  = ei + NE;
    const int*   batch = (const int*)d_in[2];
    const float* W1    = (const float*)d_in[3];
    const float* b1    = (const float*)d_in[4];
    const float* W2    = (const float*)d_in[5];
    const float* b2    = (const float*)d_in[6];
    const float* gamma = (const float*)d_in[7];
    const float* beta  = (const float*)d_in[8];
    const float* Wp1   = (const float*)d_in[9];
    const float* bp1   = (const float*)d_in[10];
    const float* Wp2   = (const float*)d_in[11];
    const float* bp2   = (const float*)d_in[12];
    float* out = (float*)d_out;

    float* m_buf  = (float*)d_ws;                    // N*128
    float* t_buf  = m_buf + (size_t)NN * 128;        // N*128
    float* node   = t_buf + (size_t)NN * 128;        // N*384
    float* pooled = node + (size_t)NN * 384;         // G*384
    float* stats  = pooled + (size_t)GG * 384;       // 256
    float* ss     = stats + 256;                     // 256
    int*   deg    = (int*)(ss + 256);                // N   (also cursor after scan3)
    int*   rowptr = deg + NN;                        // N+1
    int*   cursor = rowptr + NN + 1;                 // N
    int*   bsum   = cursor + NN;                     // NB_SCAN
    int*   boff   = bsum + NB_SCAN;                  // NB_SCAN
    int*   csr    = boff + NB_SCAN + 4;              // E

    // ---- CSR build (once per launch) ----
    hipMemsetAsync(deg, 0, NN * sizeof(int), stream);
    hist_k<<<1024, 256, 0, stream>>>(dstI, deg);
    scan1_k<<<NB_SCAN, 256, 0, stream>>>(deg, bsum);
    scan2_k<<<1, 256, 0, stream>>>(bsum, boff);
    scan3_k<<<NB_SCAN, 256, 0, stream>>>(deg, boff, rowptr, cursor);
    fill_k<<<1024, 256, 0, stream>>>(srcI, dstI, cursor, csr);

    for (int l = 0; l < 3; ++l) {
        const float* h;
        int hstride;
        if (l == 0) { h = x; hstride = 128; }
        else        { h = node + (l - 1) * 128; hstride = 384; }

        agg_k<<<6250, 256, 0, stream>>>(rowptr, csr, h, hstride, m_buf);
        hipMemsetAsync(stats, 0, 256 * sizeof(float), stream);
        {
            dim3 gg(512, 2);
            mlp_gemm_k<<<gg, 256, 0, stream>>>(m_buf, t_buf, W1 + (size_t)l * 128 * 128, b1 + l * 128, nullptr);
            mlp_gemm_k<<<gg, 256, 0, stream>>>(t_buf, m_buf, W2 + (size_t)l * 128 * 128, b2 + l * 128, stats);
        }
        bn_finalize_k<<<1, 128, 0, stream>>>(stats, gamma + l * 128, beta + l * 128, ss);
        bn_apply_k<<<1024, 256, 0, stream>>>(m_buf, ss, node, l * 128);
    }

    pool_k<<<GG, 128, 0, stream>>>(node, batch, pooled);
    proj_k<<<GG, 384, 0, stream>>>(pooled, Wp1, bp1, Wp2, bp2, out);
}